// Round 9
// baseline (167.157 us; speedup 1.0000x reference)
//
#include <hip/hip_runtime.h>
#include <hip/hip_bf16.h>

typedef __attribute__((ext_vector_type(4))) float f32x4;
typedef __attribute__((ext_vector_type(8))) short bf16x8;

#define NROWS 32768
#define DIM   2048
#define NEXP  64
#define BKF   256              // K-chunk (f32 elements) -> 1 KiB per row
#define NCH   (DIM / BKF)      // 8 chunks

__device__ __forceinline__ short f2bf(float f) {
    __hip_bfloat16 h = __float2bfloat16(f);   // RTNE
    short s;
    __builtin_memcpy(&s, &h, 2);
    return s;
}

// async global->LDS DMA, 16B per lane; LDS dest wave-uniform (HW adds lane*16).
__device__ __forceinline__ void async16(const void* g, void* l) {
    __builtin_amdgcn_global_load_lds(
        (const __attribute__((address_space(1))) unsigned int*)g,
        (__attribute__((address_space(3))) unsigned int*)l, 16, 0, 0);
}

// ---------------- Kernel A: expert prep -------------------------------------
__global__ __launch_bounds__(256) void prep_experts(
    const float* __restrict__ ek,
    short* __restrict__ ekbf,
    short* __restrict__ ekT,
    float* __restrict__ enorm)
{
    const int e = blockIdx.x;
    const int t = threadIdx.x;
    const float* row = ek + e * DIM;
    float ss = 0.f;
#pragma unroll
    for (int i = 0; i < 2; ++i) {
        const int c4 = t + i * 256;
        const float4 v = ((const float4*)row)[c4];
        ss += v.x * v.x + v.y * v.y + v.z * v.z + v.w * v.w;
        short4 b;
        b.x = f2bf(v.x); b.y = f2bf(v.y); b.z = f2bf(v.z); b.w = f2bf(v.w);
        *(short4*)(ekbf + e * DIM + c4 * 4) = b;
        const int d = c4 * 4;
        ekT[(d + 0) * NEXP + e] = b.x;
        ekT[(d + 1) * NEXP + e] = b.y;
        ekT[(d + 2) * NEXP + e] = b.z;
        ekT[(d + 3) * NEXP + e] = b.w;
    }
#pragma unroll
    for (int s = 1; s < 64; s <<= 1) ss += __shfl_xor(ss, s);
    __shared__ float red[4];
    if ((t & 63) == 0) red[t >> 6] = ss;
    __syncthreads();
    if (t == 0) enorm[e] = sqrtf(red[0] + red[1] + red[2] + red[3]);
}

// ---------------- Kernel 1: similarity (read-bound) -------------------------
// 16 rows/block, 2048 blocks, 4 waves. Wave w computes all 16 rows x experts
// [w*16, w*16+16). z staged via global_load_lds: every DMA instruction is ONE
// contiguous 1 KiB row-span (64 lanes x 16B). 4 LDS slots, 3-chunk lookahead,
// counted vmcnt, ONE barrier per chunk (overwrite distance 3). ek B-frags are
// direct L2 loads (out of the DMA FIFO; always newer than awaited z batches).
__global__ __launch_bounds__(256) void sim_kernel(
    const float* __restrict__ z,
    const short* __restrict__ ekbf,   // [64][2048] bf16
    const float* __restrict__ enorm,  // [64]
    float* __restrict__ out_sim)      // [32768][64]
{
    const int tid = threadIdx.x;
    const int w   = tid >> 6;
    const int l   = tid & 63;
    const int lr  = l & 15;
    const int lg  = l >> 4;
    const int base = blockIdx.x * 16;

    __shared__ __align__(16) float zbuf[4][16][BKF];   // 64 KiB

    f32x4 acc = f32x4{0.f, 0.f, 0.f, 0.f};
    float ss0 = 0.f, ss1 = 0.f;

    // stage chunk c_ into slot: wave w stages rows w*4 .. w*4+3, one full
    // 1 KiB span per instruction. Source 16B-unit pre-swizzled: physical
    // unit u holds logical unit u^(row&7).
    auto STAGE_Z = [&](int c_, int slot) {
#pragma unroll
        for (int i = 0; i < 4; ++i) {
            const int zr = w * 4 + i;
            async16(z + (size_t)(base + zr) * DIM + c_ * BKF
                      + (((l ^ (zr & 7)) & 63) << 2),
                    &zbuf[slot][zr][0]);
        }
    };

    STAGE_Z(0, 0); STAGE_Z(1, 1); STAGE_Z(2, 2);       // 12 DMAs/wave in flight

    const short* ebase = ekbf + (size_t)(w * 16 + lr) * DIM + lg * 8;

    for (int c = 0; c < NCH; ++c) {
        if (c < NCH - 2)       asm volatile("s_waitcnt vmcnt(8)" ::: "memory");
        else if (c == NCH - 2) asm volatile("s_waitcnt vmcnt(4)" ::: "memory");
        else                   asm volatile("s_waitcnt vmcnt(0)" ::: "memory");
        __builtin_amdgcn_s_barrier();
        __builtin_amdgcn_sched_barrier(0);
        if (c + 3 < NCH) STAGE_Z(c + 3, (c + 3) & 3);

        const int zs = c & 3;
#pragma unroll
        for (int kk = 0; kk < BKF / 32; ++kk) {
            const bf16x8 bf = *(const bf16x8*)(ebase + c * BKF + kk * 32);
            // z logical 16B-units kk*8 + lg*2 + {0,1} of row lr
            const int u0 = ((kk * 8 + lg * 2)     ^ (lr & 7)) << 4;
            const int u1 = ((kk * 8 + lg * 2 + 1) ^ (lr & 7)) << 4;
            const char* zrowp = (const char*)&zbuf[zs][lr][0];
            const float4 a0 = *(const float4*)(zrowp + u0);
            const float4 a1 = *(const float4*)(zrowp + u1);
            ss0 = fmaf(a0.x, a0.x, ss0); ss1 = fmaf(a0.y, a0.y, ss1);
            ss0 = fmaf(a0.z, a0.z, ss0); ss1 = fmaf(a0.w, a0.w, ss1);
            ss0 = fmaf(a1.x, a1.x, ss0); ss1 = fmaf(a1.y, a1.y, ss1);
            ss0 = fmaf(a1.z, a1.z, ss0); ss1 = fmaf(a1.w, a1.w, ss1);
            bf16x8 af;
            af[0] = f2bf(a0.x); af[1] = f2bf(a0.y); af[2] = f2bf(a0.z); af[3] = f2bf(a0.w);
            af[4] = f2bf(a1.x); af[5] = f2bf(a1.y); af[6] = f2bf(a1.z); af[7] = f2bf(a1.w);
            acc = __builtin_amdgcn_mfma_f32_16x16x32_bf16(af, bf, acc, 0, 0, 0);
        }
    }

    // norms (each wave computes redundantly; rows split across lg lanes)
    float ssq = ss0 + ss1;
    ssq += __shfl_xor(ssq, 16);
    ssq += __shfl_xor(ssq, 32);
    const float zn = sqrtf(ssq);                 // ||z[base+lr]||

    const float en = enorm[w * 16 + lr];
#pragma unroll
    for (int j = 0; j < 4; ++j) {
        const float znj = __shfl(zn, lg * 4 + j);
        out_sim[(size_t)(base + lg * 4 + j) * NEXP + w * 16 + lr]
            = acc[j] / fmaxf(znj * en, 1e-8f);
    }
}

// ---------------- Kernel 2: softmax + weighted combine (write-bound) --------
// Unchanged from R8: 32 rows x 1024 cols/block, grid (1024,2); every store
// instruction writes a full 1 KiB contiguous row-segment.
__global__ __launch_bounds__(256) void moe_kernel(
    const float* __restrict__ sim,    // [32768][64]
    const short* __restrict__ ekT,    // [2048][64] bf16
    float* __restrict__ out_wei)      // [32768][2048]
{
    const int tid = threadIdx.x;
    const int w   = tid >> 6;
    const int l   = tid & 63;
    const int lr  = l & 15;
    const int lg  = l >> 4;
    const int base = blockIdx.x * 32;
    const int col0 = blockIdx.y * 1024;

    __shared__ __align__(16) short WL[32][64];        // [row][e], 16B-unit XOR swizzled
    __shared__ __align__(16) float tbuf[32][260];     // block-shared 32x256 tile (+pad)

    {   // softmax: thread t -> row t>>3, experts (t&7)*8..+8
        const int r  = tid >> 3;
        const int cc = tid & 7;
        const float* sp = sim + (size_t)(base + r) * NEXP + cc * 8;
        const float4 v0 = *(const float4*)sp;
        const float4 v1 = *(const float4*)(sp + 4);
        float va[8] = {v0.x, v0.y, v0.z, v0.w, v1.x, v1.y, v1.z, v1.w};
        float m = va[0];
#pragma unroll
        for (int i = 1; i < 8; ++i) m = fmaxf(m, va[i]);
        m = fmaxf(m, __shfl_xor(m, 1));
        m = fmaxf(m, __shfl_xor(m, 2));
        m = fmaxf(m, __shfl_xor(m, 4));
        float sum = 0.f;
#pragma unroll
        for (int i = 0; i < 8; ++i) { va[i] = __expf(va[i] - m); sum += va[i]; }
        sum += __shfl_xor(sum, 1);
        sum += __shfl_xor(sum, 2);
        sum += __shfl_xor(sum, 4);
        const float inv = 1.0f / sum;
        bf16x8 wv;
#pragma unroll
        for (int i = 0; i < 8; ++i) wv[i] = f2bf(va[i] * inv);
        *(bf16x8*)&WL[r][(cc ^ (r & 7)) * 8] = wv;
    }
    __syncthreads();

    bf16x8 afr[2][2];
#pragma unroll
    for (int mt = 0; mt < 2; ++mt)
#pragma unroll
        for (int ks = 0; ks < 2; ++ks) {
            const int row = mt * 16 + lr;
            const int u   = (ks * 4 + lg) ^ (row & 7);
            afr[mt][ks] = *(const bf16x8*)&WL[row][u * 8];
        }

#pragma unroll 1
    for (int g = 0; g < 4; ++g) {
        f32x4 oacc[4][2];   // [nt2][mt]
#pragma unroll
        for (int nt2 = 0; nt2 < 4; ++nt2) {
            const int d0 = col0 + g * 256 + w * 64 + nt2 * 16;
            const short* bp = ekT + (size_t)(d0 + lr) * NEXP + lg * 8;
            const bf16x8 b0 = *(const bf16x8*)bp;
            const bf16x8 b1 = *(const bf16x8*)(bp + 32);
#pragma unroll
            for (int mt = 0; mt < 2; ++mt) {
                f32x4 o = f32x4{0.f, 0.f, 0.f, 0.f};
                o = __builtin_amdgcn_mfma_f32_16x16x32_bf16(afr[mt][0], b0, o, 0, 0, 0);
                o = __builtin_amdgcn_mfma_f32_16x16x32_bf16(afr[mt][1], b1, o, 0, 0, 0);
                oacc[nt2][mt] = o;
            }
        }
#pragma unroll
        for (int nt2 = 0; nt2 < 4; ++nt2)
#pragma unroll
            for (int mt = 0; mt < 2; ++mt)
#pragma unroll
                for (int j = 0; j < 4; ++j)
                    tbuf[mt * 16 + lg * 4 + j][w * 64 + nt2 * 16 + lr] = oacc[nt2][mt][j];
        __syncthreads();
#pragma unroll
        for (int i = 0; i < 8; ++i) {
            const int row = w * 8 + i;
            const float4 t = *(const float4*)&tbuf[row][l * 4];
            *(float4*)&out_wei[(size_t)(base + row) * DIM + col0 + g * 256 + l * 4] = t;
        }
        __syncthreads();   // before tbuf reuse
    }
}

// ---------------- launch -----------------------------------------------------
extern "C" void kernel_launch(void* const* d_in, const int* in_sizes, int n_in,
                              void* d_out, int out_size, void* d_ws, size_t ws_size,
                              hipStream_t stream) {
    const float* z  = (const float*)d_in[0];
    const float* ek = (const float*)d_in[1];
    float* out_sim = (float*)d_out;
    float* out_wei = out_sim + (size_t)NROWS * NEXP;

    short* ekbf  = (short*)d_ws;                 // 256 KiB
    short* ekT   = ekbf + NEXP * DIM;            // 256 KiB
    float* enorm = (float*)(ekT + DIM * NEXP);   // 256 B

    prep_experts<<<NEXP, 256, 0, stream>>>(ek, ekbf, ekT, enorm);
    sim_kernel<<<NROWS / 16, 256, 0, stream>>>(z, ekbf, enorm, out_sim);
    moe_kernel<<<dim3(NROWS / 32, 2), 256, 0, stream>>>(out_sim, ekT, out_wei);
}